// Round 6
// baseline (256.822 us; speedup 1.0000x reference)
//
#include <hip/hip_runtime.h>

typedef __bf16 bf16x8 __attribute__((ext_vector_type(8)));
typedef float f32x4 __attribute__((ext_vector_type(4)));

#define B_ 4
#define T_ 2048
#define D_ 1024
#define H_ 16
#define HD_ 64
#define M_ 8192
// 1/sqrt(64) * log2(e), folded into Q so softmax uses exp2
#define QSCALE 0.1803368801111204f

__device__ __forceinline__ ushort f2b(float f) {
  union { float f; unsigned u; } v; v.f = f;
  unsigned u = v.u;
  return (ushort)((u + 0x7FFFu + ((u >> 16) & 1u)) >> 16);
}

// pack two floats to bf16 pair (round-half-up: +0x8000 then take hi16)
__device__ __forceinline__ unsigned pkbf(float a, float b) {
  union { float f; unsigned u; } va, vb; va.f = a; vb.f = b;
  return __builtin_amdgcn_perm(vb.u + 0x8000u, va.u + 0x8000u, 0x07060302u);
}

// async global->LDS, 16B per lane. LDS dest must be wave-uniform base + lane*16.
__device__ __forceinline__ void gll16(const void* g, void* l) {
  __builtin_amdgcn_global_load_lds(
      (const __attribute__((address_space(1))) unsigned*)g,
      (__attribute__((address_space(3))) unsigned*)l, 16, 0, 0);
}

__global__ __launch_bounds__(256) void cast_x_kernel(const float* __restrict__ x,
                                                     ushort* __restrict__ xb) {
  int idx = blockIdx.x * 256 + threadIdx.x;
  float4 v = ((const float4*)x)[idx];
  ushort4 o;
  o.x = f2b(v.x); o.y = f2b(v.y); o.z = f2b(v.z); o.w = f2b(v.w);
  ((ushort4*)xb)[idx] = o;
}

// 32x32 tiled transpose+cast: dst[n][k] = src[k][n], bf16 out
__global__ __launch_bounds__(256) void transpose_w_kernel(
    const float* __restrict__ wq, const float* __restrict__ wk,
    const float* __restrict__ wv, const float* __restrict__ wo,
    ushort* __restrict__ wt_qkv, ushort* __restrict__ wt_o) {
  __shared__ float tile[32][33];
  int z = blockIdx.z;
  const float* src = (z == 0) ? wq : (z == 1) ? wk : (z == 2) ? wv : wo;
  ushort* dst = (z < 3) ? (wt_qkv + (size_t)z * D_ * D_) : wt_o;
  int n0 = blockIdx.x * 32, k0 = blockIdx.y * 32;
  int tx = threadIdx.x & 31, ty = threadIdx.x >> 5;
  for (int i = 0; i < 4; i++) {
    int r = ty + i * 8;
    tile[r][tx] = src[(size_t)(k0 + r) * D_ + n0 + tx];
  }
  __syncthreads();
  for (int i = 0; i < 4; i++) {
    int r = ty + i * 8;
    dst[(size_t)(n0 + r) * D_ + k0 + tx] = f2b(tile[tx][r]);
  }
}

// C = A(MxK) * Bt(NxK)^T. Round-6: T3+T4 deep-pipelined structure.
// BM=256 x BN=128, BK=64, 512 threads = 8 waves (4M x 2N), wave-tile 64x64.
// TRIPLE-buffered LDS (3 x 48KB = 144KB dynamic): while computing tile t
// (buf t%3), tile t+2 is staged into buf (t+2)%3 — the buffer whose reads
// (tile t-1) completed at the barrier ending tile t-1. Counted vmcnt at each
// tile boundary: per-thread load FIFO is 6 loads/tile, so "tile t+1 landed"
// = "<= 6 outstanding" -> s_waitcnt vmcnt(6); NEVER 0 in steady state (the
// T4 win: loads span barriers). Each phase: {8 ds_read_b128 || issue 2-3
// global_load_lds -> barrier -> setprio(1) 16 MFMA setprio(0) -> barrier}.
// Swizzle (both-sides chunk XOR by row&7) carried over: measured 0 conflicts.
// K-accumulation order identical to round 4/5 -> bit-exact C.
__global__ __launch_bounds__(512) void gemm_kernel(
    const ushort* __restrict__ A, const ushort* __restrict__ Bt, int mode,
    const float* __restrict__ bias_q, const float* __restrict__ bias_k,
    const float* __restrict__ bias_v,
    ushort* __restrict__ qb, ushort* __restrict__ kb, ushort* __restrict__ vtb,
    float* __restrict__ outf) {
  extern __shared__ char lds_raw[];
  ushort (*As)[256][64] = (ushort (*)[256][64])lds_raw;            // 3x32KB
  ushort (*Bs)[128][64] = (ushort (*)[128][64])(lds_raw + 98304);  // 3x16KB
  int tid = threadIdx.x;
  int wave = tid >> 6, lane = tid & 63, lrow = lane >> 4, lcol = lane & 15;
  int wr = wave >> 1, wc = wave & 1;  // 4M x 2N wave grid

  // XCD-chunked remap; nwg = 768 (mode0) / 256 (mode1), both %8==0.
  int gx = gridDim.x;
  int nwg = gx * gridDim.y;
  int orig = blockIdx.x + gx * blockIdx.y;
  int work = (orig & 7) * (nwg >> 3) + (orig >> 3);
  int m0 = (work / gx) * 256, n0 = (work % gx) * 128;

  // staging geometry: 512 threads; A-unit = 128 rows x 64 cols (16KB) ->
  // 2 gll16/thread; per K-tile: A-unit0, A-unit1, B (3 units, 6 loads).
  int r_s = tid >> 3, c_s = tid & 7;
  int scv = c_s ^ (r_s & 7);  // pre-swizzled source chunk ((r+64k)&7 == r&7)
  const ushort* aB = A + (size_t)(m0 + r_s) * D_ + scv * 8;
  const ushort* bB = Bt + (size_t)(n0 + r_s) * D_ + scv * 8;

  auto stageA = [&](int buf, int t, int u) {
    const ushort* s = aB + (size_t)u * 128 * D_ + t * 64;
    char* d = (char*)&As[buf][0][0] + u * 16384 + tid * 16;
    gll16(s, d);
    gll16(s + (size_t)64 * D_, d + 8192);
  };
  auto stageB = [&](int buf, int t) {
    const ushort* s = bB + t * 64;
    char* d = (char*)&Bs[buf][0][0] + tid * 16;
    gll16(s, d);
    gll16(s + (size_t)64 * D_, d + 8192);
  };

  f32x4 zero = {0.f, 0.f, 0.f, 0.f};
  f32x4 acc[4][4];
  for (int i = 0; i < 4; i++)
    for (int j = 0; j < 4; j++) acc[i][j] = zero;

  int swz = lcol & 7;

  // prologue: stage tiles 0 and 1 (FIFO order matters for vmcnt accounting)
  stageA(0, 0, 0); stageA(0, 0, 1); stageB(0, 0);
  stageA(1, 1, 0); stageA(1, 1, 1); stageB(1, 1);
  asm volatile("s_waitcnt vmcnt(6)" ::: "memory");  // tile 0 landed
  __builtin_amdgcn_sched_barrier(0);
  __builtin_amdgcn_s_barrier();

#pragma unroll
  for (int t = 0; t < 16; ++t) {
    int buf = t % 3;          // compile-time after unroll
    int nb = (t + 2) % 3;
#pragma unroll
    for (int ks = 0; ks < 2; ++ks) {
      bf16x8 af[4], bf[4];
      int ch = ((ks * 4 + lrow) ^ swz) * 8;
#pragma unroll
      for (int mt = 0; mt < 4; mt++)
        af[mt] = *(const bf16x8*)&As[buf][wr * 64 + mt * 16 + lcol][ch];
#pragma unroll
      for (int nt = 0; nt < 4; nt++)
        bf[nt] = *(const bf16x8*)&Bs[buf][wc * 64 + nt * 16 + lcol][ch];
      if (t + 2 < 16) {
        if (ks == 0) { stageA(nb, t + 2, 0); stageA(nb, t + 2, 1); }
        else         { stageB(nb, t + 2); }
      }
      __builtin_amdgcn_sched_barrier(0);
      __builtin_amdgcn_s_barrier();          // reads+issues clustered
      __builtin_amdgcn_sched_barrier(0);
      __builtin_amdgcn_s_setprio(1);
#pragma unroll
      for (int mt = 0; mt < 4; mt++)
#pragma unroll
        for (int nt = 0; nt < 4; nt++)
          acc[mt][nt] = __builtin_amdgcn_mfma_f32_16x16x32_bf16(
              af[mt], bf[nt], acc[mt][nt], 0, 0, 0);
      __builtin_amdgcn_s_setprio(0);
      if (ks == 1) {  // tile-boundary checkpoint: next tile's data must be in
        if (t <= 13) {
          asm volatile("s_waitcnt vmcnt(6)" ::: "memory");  // t+2 in flight
        } else if (t == 14) {
          asm volatile("s_waitcnt vmcnt(0)" ::: "memory");  // final drain
        }
      }
      __builtin_amdgcn_sched_barrier(0);
      __builtin_amdgcn_s_barrier();
    }
  }

  if (mode == 0) {
    int proj = n0 >> 10;  // uniform per block (128 | 1024)
    const float* bias = (proj == 0) ? bias_q : (proj == 1) ? bias_k : bias_v;
    for (int mt = 0; mt < 4; mt++) {
      int gm0 = m0 + wr * 64 + mt * 16 + lrow * 4;  // 4 consecutive t, same b
      int b = gm0 >> 11, tp = gm0 & 2047;
      for (int nt = 0; nt < 4; nt++) {
        int gn = n0 + wc * 64 + nt * 16 + lcol;
        int inner = gn & 1023;
        int h = inner >> 6, hd = inner & 63;
        float bv = bias[inner];
        if (proj == 0) {
          size_t base = ((size_t)(b * H_ + h) * T_ + tp) * HD_ + hd;
          for (int r = 0; r < 4; r++)
            qb[base + (size_t)r * HD_] = f2b((acc[mt][nt][r] + bv) * QSCALE);
        } else if (proj == 1) {
          size_t base = ((size_t)(b * H_ + h) * T_ + tp) * HD_ + hd;
          for (int r = 0; r < 4; r++)
            kb[base + (size_t)r * HD_] = f2b(acc[mt][nt][r] + bv);
        } else {  // V stored transposed: (B,H,HD,T); 4 t's pack into ushort4
          ushort4 pk;
          pk.x = f2b(acc[mt][nt][0] + bv);
          pk.y = f2b(acc[mt][nt][1] + bv);
          pk.z = f2b(acc[mt][nt][2] + bv);
          pk.w = f2b(acc[mt][nt][3] + bv);
          *(ushort4*)&vtb[((size_t)(b * H_ + h) * HD_ + hd) * T_ + tp] = pk;
        }
      }
    }
  } else {
    for (int mt = 0; mt < 4; mt++) {
      int gm0 = m0 + wr * 64 + mt * 16 + lrow * 4;
      for (int nt = 0; nt < 4; nt++) {
        int gn = n0 + wc * 64 + nt * 16 + lcol;
        float bv = bias_q[gn];
        for (int r = 0; r < 4; r++)
          outf[(size_t)(gm0 + r) * D_ + gn] = acc[mt][nt][r] + bv;
      }
    }
  }
}

// Causal flash attention, fixed-base softmax (log2-unit scores, exp2, no max
// subtraction — validated). Round-5 structure: MERGED pair loop (unchanged).
#define QCOMP(qblk_, q0w_, qfv, accOv, accSv)                                   \
  do {                                                                          \
    f32x4 st[2][4];                                                             \
    for (int qh = 0; qh < 2; qh++)                                              \
      for (int mt = 0; mt < 4; mt++) st[qh][mt] = zero;                         \
    __builtin_amdgcn_s_setprio(1);                                              \
    _Pragma("unroll")                                                           \
    for (int ks = 0; ks < 2; ks++)                                              \
      _Pragma("unroll")                                                         \
      for (int mt = 0; mt < 4; mt++) {                                          \
        bf16x8 kf = *(const bf16x8*)&Ks2[cur][mt * 16 + lcol]                   \
                                        [((ks * 4 + lrow) ^ rsw) * 8];          \
        st[0][mt] = __builtin_amdgcn_mfma_f32_16x16x32_bf16(kf, qfv[0][ks],     \
                                                            st[0][mt], 0, 0, 0);\
        st[1][mt] = __builtin_amdgcn_mfma_f32_16x16x32_bf16(kf, qfv[1][ks],     \
                                                            st[1][mt], 0, 0, 0);\
      }                                                                         \
    __builtin_amdgcn_s_setprio(0);                                              \
    if (j >= 2 * (qblk_)) {                                                     \
      _Pragma("unroll")                                                         \
      for (int qh = 0; qh < 2; qh++) {                                          \
        int q_g = (q0w_) + qh * 16 + lcol;                                      \
        _Pragma("unroll")                                                       \
        for (int mt = 0; mt < 4; mt++)                                          \
          for (int r = 0; r < 4; r++) {                                         \
            int kv_g = j * 64 + mt * 16 + lrow * 4 + r;                         \
            if (kv_g > q_g) st[qh][mt][r] = -1e30f;                             \
          }                                                                     \
      }                                                                         \
    }                                                                           \
    _Pragma("unroll")                                                           \
    for (int qh = 0; qh < 2; qh++)                                              \
      for (int mt = 0; mt < 4; mt++)                                            \
        for (int r = 0; r < 4; r++)                                             \
          st[qh][mt][r] = __builtin_amdgcn_exp2f(st[qh][mt][r]);                \
    _Pragma("unroll")                                                           \
    for (int qh = 0; qh < 2; qh++)                                              \
      for (int mt = 0; mt < 4; mt++) {                                          \
        uint2 pk;                                                               \
        pk.x = pkbf(st[qh][mt][0], st[qh][mt][1]);                              \
        pk.y = pkbf(st[qh][mt][2], st[qh][mt][3]);                              \
        int sl = ((2 * mt + (lrow >> 1)) ^ rsw) * 8 + (lrow & 1) * 4;           \
        *(uint2*)&Ps[wave][qh * 16 + lcol][sl] = pk;                            \
      }                                                                         \
    __builtin_amdgcn_s_setprio(1);                                              \
    _Pragma("unroll")                                                           \
    for (int ks = 0; ks < 2; ks++) {                                            \
      int ch = ((ks * 4 + lrow) ^ rsw) * 8;                                     \
      bf16x8 pf0 = *(const bf16x8*)&Ps[wave][lcol][ch];                         \
      bf16x8 pf1 = *(const bf16x8*)&Ps[wave][16 + lcol][ch];                    \
      accSv[0] = __builtin_amdgcn_mfma_f32_16x16x32_bf16(af1, pf0, accSv[0],    \
                                                         0, 0, 0);              \
      accSv[1] = __builtin_amdgcn_mfma_f32_16x16x32_bf16(af1, pf1, accSv[1],    \
                                                         0, 0, 0);              \
      _Pragma("unroll")                                                         \
      for (int mt = 0; mt < 4; mt++) {                                          \
        bf16x8 vf = *(const bf16x8*)&Vs2[cur][mt * 16 + lcol][ch];              \
        accOv[0][mt] = __builtin_amdgcn_mfma_f32_16x16x32_bf16(vf, pf0,         \
                                                    accOv[0][mt], 0, 0, 0);     \
        accOv[1][mt] = __builtin_amdgcn_mfma_f32_16x16x32_bf16(vf, pf1,         \
                                                    accOv[1][mt], 0, 0, 0);     \
      }                                                                         \
    }                                                                           \
    __builtin_amdgcn_s_setprio(0);                                              \
  } while (0)

__global__ __launch_bounds__(256) void flash_kernel(
    const ushort* __restrict__ qb, const ushort* __restrict__ kb,
    const ushort* __restrict__ vtb, ushort* __restrict__ ob) {
  __shared__ ushort Ks2[2][64][64];  // 16 KB  [buf][kv][hd] (swizzled chunks)
  __shared__ ushort Vs2[2][64][64];  // 16 KB  [buf][hd][kv] (swizzled chunks)
  __shared__ ushort Ps[4][32][64];   // 16 KB  per-wave P^T strip (swizzled)
  int tid = threadIdx.x;
  int wave = tid >> 6, lane = tid & 63, lrow = lane >> 4, lcol = lane & 15;

  int bid = blockIdx.x + (blockIdx.y << 3);  // grid (8,64) -> 0..511
  int xcd = bid & 7;                         // HW round-robin XCD id
  int slot = bid >> 3;                       // 0..63 per XCD
  int phase = slot >> 5;                     // slot s and s+32 -> same CU
  int j5 = slot & 31;
  int pm = j5 & 7;
  int bh = xcd * 8 + (j5 >> 3) + phase * 4;  // 8 bh per XCD -> K/V L2-resident
  int p = phase ? 7 - pm : pm;               // CU pair carries (p, 7-p): 50 units
  int qbA = 15 - p, qbB = p;
  int b = bh >> 4, h = bh & 15;
  const ushort* qp = qb + (size_t)bh * T_ * HD_;
  const ushort* kh = kb + (size_t)bh * T_ * HD_;
  const ushort* vh = vtb + (size_t)bh * HD_ * T_;

  int njA = 2 * qbA + 2, njB = 2 * qbB + 2;  // B's tiles are a prefix of A's

  int r0 = tid >> 3, dc = tid & 7;          // staging: row, 16B chunk
  int wsl = (dc ^ (r0 & 7)) * 8;            // swizzled slot (ushort offset)
  int rsw = lcol & 7;                       // read-side swizzle key

  uint4 kr0, kr1, vr0, vr1;                 // prefetch regs (one KV tile)
  auto gload = [&](int jt) {
    kr0 = *(const uint4*)&kh[(size_t)(jt * 64 + r0) * HD_ + dc * 8];
    kr1 = *(const uint4*)&kh[(size_t)(jt * 64 + r0 + 32) * HD_ + dc * 8];
    vr0 = *(const uint4*)&vh[(size_t)r0 * T_ + jt * 64 + dc * 8];
    vr1 = *(const uint4*)&vh[(size_t)(r0 + 32) * T_ + jt * 64 + dc * 8];
  };
  auto swrite = [&](int buf) {
    *(uint4*)&Ks2[buf][r0][wsl] = kr0;
    *(uint4*)&Ks2[buf][r0 + 32][wsl] = kr1;   // (r0+32)&7 == r0&7
    *(uint4*)&Vs2[buf][r0][wsl] = vr0;
    *(uint4*)&Vs2[buf][r0 + 32][wsl] = vr1;
  };

  // constant ones-row A-fragment: A[m=0][*]=1, A[m>0][*]=0 (m = lcol)
  bf16x8 af1;
  {
    __bf16 ov = (__bf16)((lcol == 0) ? 1.0f : 0.0f);
    for (int i2 = 0; i2 < 8; i2++) af1[i2] = ov;
  }

  f32x4 zero = {0.f, 0.f, 0.f, 0.f};

  // prologue: tile 0 -> buf0; prefetch tile 1
  gload(0);
  swrite(0);
  gload(1);
  __syncthreads();

  int q0wA = qbA * 128 + wave * 32, q0wB = qbB * 128 + wave * 32;
  bf16x8 qfA[2][2], qfB[2][2];
#pragma unroll
  for (int qh = 0; qh < 2; qh++)
#pragma unroll
    for (int ks = 0; ks < 2; ks++) {
      qfA[qh][ks] = *(const bf16x8*)&qp[(size_t)(q0wA + qh * 16 + lcol) * HD_ +
                                        ks * 32 + lrow * 8];
      qfB[qh][ks] = *(const bf16x8*)&qp[(size_t)(q0wB + qh * 16 + lcol) * HD_ +
                                        ks * 32 + lrow * 8];
    }

  f32x4 accOA[2][4], accOB[2][4];
  f32x4 accSA[2], accSB[2];
#pragma unroll
  for (int qh = 0; qh < 2; qh++) {
    accSA[qh] = zero; accSB[qh] = zero;
    for (int mt = 0; mt < 4; mt++) { accOA[qh][mt] = zero; accOB[qh][mt] = zero; }
  }

  for (int j = 0; j < njA; j++) {
    int cur = j & 1;
    if (j * 64 <= q0wA + 31) QCOMP(qbA, q0wA, qfA, accOA, accSA);
    if (j * 64 <= q0wB + 31) QCOMP(qbB, q0wB, qfB, accOB, accSB);
    // stage next tile (regs hold tile j+1) into the other buffer; its old
    // readers finished before the PREVIOUS barrier.
    if (j + 1 < njA) swrite(cur ^ 1);
    if (j + 2 < njA) gload(j + 2);
    __syncthreads();  // publish writes for next iteration
  }
  (void)njB;

  // epilogue per q-block / q-half
#pragma unroll
  for (int qh = 0; qh < 2; qh++) {
    float lsum = __shfl(accSA[qh][0], lcol);
    float linv = 1.f / lsum;
    int t = q0wA + qh * 16 + lcol;
    size_t base2 = ((size_t)b * T_ + t) * D_ + h * HD_;
#pragma unroll
    for (int mt = 0; mt < 4; mt++) {
      uint2 pk;
      pk.x = pkbf(accOA[qh][mt][0] * linv, accOA[qh][mt][1] * linv);
      pk.y = pkbf(accOA[qh][mt][2] * linv, accOA[qh][mt][3] * linv);
      *(uint2*)&ob[base2 + mt * 16 + lrow * 4] = pk;
    }
  }
#pragma unroll
  for (int qh = 0; qh < 2; qh++) {
    float lsum = __shfl(accSB[qh][0], lcol);
    float linv = 1.f / lsum;
    int t = q0wB + qh * 16 + lcol;
    size_t base2 = ((size_t)b * T_ + t) * D_ + h * HD_;
#pragma unroll
    for (int mt = 0; mt < 4; mt++) {
      uint2 pk;
      pk.x = pkbf(accOB[qh][mt][0] * linv, accOB[qh][mt][1] * linv);
      pk.y = pkbf(accOB[qh][mt][2] * linv, accOB[qh][mt][3] * linv);
      *(uint2*)&ob[base2 + mt * 16 + lrow * 4] = pk;
    }
  }
}

extern "C" void kernel_launch(void* const* d_in, const int* in_sizes, int n_in,
                              void* d_out, int out_size, void* d_ws, size_t ws_size,
                              hipStream_t stream) {
  (void)in_sizes; (void)n_in; (void)out_size; (void)ws_size;
  const float* x  = (const float*)d_in[0];
  const float* wq = (const float*)d_in[1];
  const float* bq = (const float*)d_in[2];
  const float* wk = (const float*)d_in[3];
  const float* bk = (const float*)d_in[4];
  const float* wv = (const float*)d_in[5];
  const float* bv = (const float*)d_in[6];
  const float* wo = (const float*)d_in[7];
  const float* bo = (const float*)d_in[8];
  float* out = (float*)d_out;

  char* ws = (char*)d_ws;
  ushort* xb     = (ushort*)(ws);              // 16 MB  x as bf16 (M x K)
  ushort* wt_qkv = (ushort*)(ws + 16777216);   // 6 MB   [wq|wk|wv]^T (3072 x 1024)
  ushort* wt_o   = (ushort*)(ws + 23068672);   // 2 MB   wo^T
  ushort* qb     = (ushort*)(ws + 25165824);   // 16 MB  Q (B,H,T,HD), pre-scaled
  ushort* kb     = (ushort*)(ws + 41943040);   // 16 MB  K (B,H,T,HD)
  ushort* vtb    = (ushort*)(ws + 58720256);   // 16 MB  V (B,H,HD,T)
  ushort* ob     = (ushort*)(ws + 75497472);   // 16 MB  attn out (B,T,D)

  // allow 144KB dynamic LDS for the pipelined GEMM (host-side attribute,
  // capture-safe: not a stream op; idempotent)
  hipFuncSetAttribute((const void*)gemm_kernel,
                      hipFuncAttributeMaxDynamicSharedMemorySize, 147456);

  cast_x_kernel<<<8192, 256, 0, stream>>>(x, xb);
  transpose_w_kernel<<<dim3(32, 32, 4), 256, 0, stream>>>(wq, wk, wv, wo, wt_qkv, wt_o);
  gemm_kernel<<<dim3(24, 32), 512, 147456, stream>>>(xb, wt_qkv, 0, bq, bk, bv, qb, kb, vtb, nullptr);
  flash_kernel<<<dim3(8, 64), 256, 0, stream>>>(qb, kb, vtb, ob);
  gemm_kernel<<<dim3(8, 32), 512, 147456, stream>>>(ob, wt_o, 1, bo, nullptr, nullptr,
                                                    nullptr, nullptr, nullptr, out);
}

// Round 7
// 237.710 us; speedup vs baseline: 1.0804x; 1.0804x over previous
//
#include <hip/hip_runtime.h>

typedef __bf16 bf16x8 __attribute__((ext_vector_type(8)));
typedef float f32x4 __attribute__((ext_vector_type(4)));

#define B_ 4
#define T_ 2048
#define D_ 1024
#define H_ 16
#define HD_ 64
#define M_ 8192
// 1/sqrt(64) * log2(e), folded into Q so softmax uses exp2
#define QSCALE 0.1803368801111204f

__device__ __forceinline__ ushort f2b(float f) {
  union { float f; unsigned u; } v; v.f = f;
  unsigned u = v.u;
  return (ushort)((u + 0x7FFFu + ((u >> 16) & 1u)) >> 16);
}

// pack two floats to bf16 pair (round-half-up: +0x8000 then take hi16)
__device__ __forceinline__ unsigned pkbf(float a, float b) {
  union { float f; unsigned u; } va, vb; va.f = a; vb.f = b;
  return __builtin_amdgcn_perm(vb.u + 0x8000u, va.u + 0x8000u, 0x07060302u);
}

// async global->LDS, 16B per lane. LDS dest must be wave-uniform base + lane*16.
__device__ __forceinline__ void gll16(const void* g, void* l) {
  __builtin_amdgcn_global_load_lds(
      (const __attribute__((address_space(1))) unsigned*)g,
      (__attribute__((address_space(3))) unsigned*)l, 16, 0, 0);
}

__global__ __launch_bounds__(256) void cast_x_kernel(const float* __restrict__ x,
                                                     ushort* __restrict__ xb) {
  int idx = blockIdx.x * 256 + threadIdx.x;
  float4 v = ((const float4*)x)[idx];
  ushort4 o;
  o.x = f2b(v.x); o.y = f2b(v.y); o.z = f2b(v.z); o.w = f2b(v.w);
  ((ushort4*)xb)[idx] = o;
}

// 32x32 tiled transpose+cast: dst[n][k] = src[k][n], bf16 out
__global__ __launch_bounds__(256) void transpose_w_kernel(
    const float* __restrict__ wq, const float* __restrict__ wk,
    const float* __restrict__ wv, const float* __restrict__ wo,
    ushort* __restrict__ wt_qkv, ushort* __restrict__ wt_o) {
  __shared__ float tile[32][33];
  int z = blockIdx.z;
  const float* src = (z == 0) ? wq : (z == 1) ? wk : (z == 2) ? wv : wo;
  ushort* dst = (z < 3) ? (wt_qkv + (size_t)z * D_ * D_) : wt_o;
  int n0 = blockIdx.x * 32, k0 = blockIdx.y * 32;
  int tx = threadIdx.x & 31, ty = threadIdx.x >> 5;
  for (int i = 0; i < 4; i++) {
    int r = ty + i * 8;
    tile[r][tx] = src[(size_t)(k0 + r) * D_ + n0 + tx];
  }
  __syncthreads();
  for (int i = 0; i < 4; i++) {
    int r = ty + i * 8;
    dst[(size_t)(n0 + r) * D_ + k0 + tx] = f2b(tile[tx][r]);
  }
}

// MODE-0 GEMM (QKV projections): round-6 pipelined structure, measured 66.5us.
// BM=256 x BN=128, BK=64, 512 threads = 8 waves (4M x 2N), wave-tile 64x64.
// Triple-buffered LDS (3 x 48KB = 144KB dynamic), counted vmcnt(6) at tile
// boundaries (never 0 in steady state), per-phase {ds_read || stage -> barrier
// -> setprio MFMA -> barrier}. Swizzle both-sides (0 conflicts measured).
__global__ __launch_bounds__(512) void gemm_pipe_kernel(
    const ushort* __restrict__ A, const ushort* __restrict__ Bt,
    const float* __restrict__ bias_q, const float* __restrict__ bias_k,
    const float* __restrict__ bias_v,
    ushort* __restrict__ qb, ushort* __restrict__ kb, ushort* __restrict__ vtb) {
  extern __shared__ char lds_raw[];
  ushort (*As)[256][64] = (ushort (*)[256][64])lds_raw;            // 3x32KB
  ushort (*Bs)[128][64] = (ushort (*)[128][64])(lds_raw + 98304);  // 3x16KB
  int tid = threadIdx.x;
  int wave = tid >> 6, lane = tid & 63, lrow = lane >> 4, lcol = lane & 15;
  int wr = wave >> 1, wc = wave & 1;  // 4M x 2N wave grid

  // XCD-chunked remap; nwg = 768, %8==0.
  int gx = gridDim.x;
  int nwg = gx * gridDim.y;
  int orig = blockIdx.x + gx * blockIdx.y;
  int work = (orig & 7) * (nwg >> 3) + (orig >> 3);
  int m0 = (work / gx) * 256, n0 = (work % gx) * 128;

  // staging geometry: 512 threads; A-unit = 128 rows x 64 cols (16KB) ->
  // 2 gll16/thread; per K-tile: A-unit0, A-unit1, B (3 units, 6 loads).
  int r_s = tid >> 3, c_s = tid & 7;
  int scv = c_s ^ (r_s & 7);  // pre-swizzled source chunk ((r+64k)&7 == r&7)
  const ushort* aB = A + (size_t)(m0 + r_s) * D_ + scv * 8;
  const ushort* bB = Bt + (size_t)(n0 + r_s) * D_ + scv * 8;

  auto stageA = [&](int buf, int t, int u) {
    const ushort* s = aB + (size_t)u * 128 * D_ + t * 64;
    char* d = (char*)&As[buf][0][0] + u * 16384 + tid * 16;
    gll16(s, d);
    gll16(s + (size_t)64 * D_, d + 8192);
  };
  auto stageB = [&](int buf, int t) {
    const ushort* s = bB + t * 64;
    char* d = (char*)&Bs[buf][0][0] + tid * 16;
    gll16(s, d);
    gll16(s + (size_t)64 * D_, d + 8192);
  };

  f32x4 zero = {0.f, 0.f, 0.f, 0.f};
  f32x4 acc[4][4];
  for (int i = 0; i < 4; i++)
    for (int j = 0; j < 4; j++) acc[i][j] = zero;

  int swz = lcol & 7;

  // prologue: stage tiles 0 and 1 (FIFO order matters for vmcnt accounting)
  stageA(0, 0, 0); stageA(0, 0, 1); stageB(0, 0);
  stageA(1, 1, 0); stageA(1, 1, 1); stageB(1, 1);
  asm volatile("s_waitcnt vmcnt(6)" ::: "memory");  // tile 0 landed
  __builtin_amdgcn_sched_barrier(0);
  __builtin_amdgcn_s_barrier();

#pragma unroll
  for (int t = 0; t < 16; ++t) {
    int buf = t % 3;          // compile-time after unroll
    int nb = (t + 2) % 3;
#pragma unroll
    for (int ks = 0; ks < 2; ++ks) {
      bf16x8 af[4], bf[4];
      int ch = ((ks * 4 + lrow) ^ swz) * 8;
#pragma unroll
      for (int mt = 0; mt < 4; mt++)
        af[mt] = *(const bf16x8*)&As[buf][wr * 64 + mt * 16 + lcol][ch];
#pragma unroll
      for (int nt = 0; nt < 4; nt++)
        bf[nt] = *(const bf16x8*)&Bs[buf][wc * 64 + nt * 16 + lcol][ch];
      if (t + 2 < 16) {
        if (ks == 0) { stageA(nb, t + 2, 0); stageA(nb, t + 2, 1); }
        else         { stageB(nb, t + 2); }
      }
      __builtin_amdgcn_sched_barrier(0);
      __builtin_amdgcn_s_barrier();          // reads+issues clustered
      __builtin_amdgcn_sched_barrier(0);
      __builtin_amdgcn_s_setprio(1);
#pragma unroll
      for (int mt = 0; mt < 4; mt++)
#pragma unroll
        for (int nt = 0; nt < 4; nt++)
          acc[mt][nt] = __builtin_amdgcn_mfma_f32_16x16x32_bf16(
              af[mt], bf[nt], acc[mt][nt], 0, 0, 0);
      __builtin_amdgcn_s_setprio(0);
      if (ks == 1) {  // tile-boundary checkpoint: next tile's data must be in
        if (t <= 13) {
          asm volatile("s_waitcnt vmcnt(6)" ::: "memory");  // t+2 in flight
        } else if (t == 14) {
          asm volatile("s_waitcnt vmcnt(0)" ::: "memory");  // final drain
        }
      }
      __builtin_amdgcn_sched_barrier(0);
      __builtin_amdgcn_s_barrier();
    }
  }

  {
    int proj = n0 >> 10;  // uniform per block (128 | 1024)
    const float* bias = (proj == 0) ? bias_q : (proj == 1) ? bias_k : bias_v;
    for (int mt = 0; mt < 4; mt++) {
      int gm0 = m0 + wr * 64 + mt * 16 + lrow * 4;  // 4 consecutive t, same b
      int b = gm0 >> 11, tp = gm0 & 2047;
      for (int nt = 0; nt < 4; nt++) {
        int gn = n0 + wc * 64 + nt * 16 + lcol;
        int inner = gn & 1023;
        int h = inner >> 6, hd = inner & 63;
        float bv = bias[inner];
        if (proj == 0) {
          size_t base = ((size_t)(b * H_ + h) * T_ + tp) * HD_ + hd;
          for (int r = 0; r < 4; r++)
            qb[base + (size_t)r * HD_] = f2b((acc[mt][nt][r] + bv) * QSCALE);
        } else if (proj == 1) {
          size_t base = ((size_t)(b * H_ + h) * T_ + tp) * HD_ + hd;
          for (int r = 0; r < 4; r++)
            kb[base + (size_t)r * HD_] = f2b(acc[mt][nt][r] + bv);
        } else {  // V stored transposed: (B,H,HD,T); 4 t's pack into ushort4
          ushort4 pk;
          pk.x = f2b(acc[mt][nt][0] + bv);
          pk.y = f2b(acc[mt][nt][1] + bv);
          pk.z = f2b(acc[mt][nt][2] + bv);
          pk.w = f2b(acc[mt][nt][3] + bv);
          *(ushort4*)&vtb[((size_t)(b * H_ + h) * HD_ + hd) * T_ + tp] = pk;
        }
      }
    }
  }
}

// MODE-1 GEMM (output projection): round-4/5 static 128x128 m97 structure,
// 256 threads, 64KB LDS -> 2 blocks/CU co-residency (measured ~24us at this
// shape; the 144KB pipelined kernel at 1 block/CU regressed it to ~38us).
__global__ __launch_bounds__(256) void gemm_o_kernel(
    const ushort* __restrict__ A, const ushort* __restrict__ Bt,
    const float* __restrict__ bias, float* __restrict__ outf) {
  __shared__ ushort As[2][128][64];  // 32 KB
  __shared__ ushort Bs[2][128][64];  // 32 KB
  int tid = threadIdx.x;
  int wave = tid >> 6, lane = tid & 63, lrow = lane >> 4, lcol = lane & 15;

  int gx = gridDim.x;
  int nwg = gx * gridDim.y;
  int orig = blockIdx.x + gx * blockIdx.y;
  int work = (orig & 7) * (nwg >> 3) + (orig >> 3);
  int m0 = (work / gx) * 128, n0 = (work % gx) * 128;
  int wm = (wave & 1) * 64, wn = (wave >> 1) * 64;

  int rb = tid >> 3;            // 0..31
  int dc = tid & 7;             // dest 16B chunk
  int scv = dc ^ (rb & 7);      // swizzled source chunk
  const ushort* aBase = A + (size_t)(m0 + rb) * D_ + scv * 8;
  const ushort* bBase = Bt + (size_t)(n0 + rb) * D_ + scv * 8;

  f32x4 zero = {0.f, 0.f, 0.f, 0.f};
  f32x4 acc[4][4];
  for (int i = 0; i < 4; i++)
    for (int j = 0; j < 4; j++) acc[i][j] = zero;

  int swz = lcol & 7;

  auto stage = [&](int buf, int k) {
#pragma unroll
    for (int g = 0; g < 4; g++) {
      gll16(aBase + (size_t)(32 * g) * D_ + k, &As[buf][0][0] + tid * 8 + g * 2048);
      gll16(bBase + (size_t)(32 * g) * D_ + k, &Bs[buf][0][0] + tid * 8 + g * 2048);
    }
  };

  stage(0, 0);  // prologue

  for (int k0 = 0; k0 < D_; k0 += 64) {
    int cur = (k0 >> 6) & 1, nxt = cur ^ 1;
    __syncthreads();  // drains vmcnt -> buf[cur] ready; prior reads of nxt done
    if (k0 + 64 < D_) stage(nxt, k0 + 64);  // async, in flight across compute

    for (int ks = 0; ks < 2; ks++) {
      bf16x8 af[4], bf[4];
      int ch = ((ks * 4 + lrow) ^ swz) * 8;
      for (int mt = 0; mt < 4; mt++)
        af[mt] = *(const bf16x8*)&As[cur][wm + mt * 16 + lcol][ch];
      for (int nt = 0; nt < 4; nt++)
        bf[nt] = *(const bf16x8*)&Bs[cur][wn + nt * 16 + lcol][ch];
      for (int mt = 0; mt < 4; mt++)
        for (int nt = 0; nt < 4; nt++)
          acc[mt][nt] = __builtin_amdgcn_mfma_f32_16x16x32_bf16(
              af[mt], bf[nt], acc[mt][nt], 0, 0, 0);
    }
  }

  for (int mt = 0; mt < 4; mt++) {
    int gm0 = m0 + wm + mt * 16 + lrow * 4;
    for (int nt = 0; nt < 4; nt++) {
      int gn = n0 + wn + nt * 16 + lcol;
      float bv = bias[gn];
      for (int r = 0; r < 4; r++)
        outf[(size_t)(gm0 + r) * D_ + gn] = acc[mt][nt][r] + bv;
    }
  }
}

// Causal flash attention, fixed-base softmax (log2-unit scores, exp2, no max
// subtraction — validated). Round-5 structure: MERGED pair loop (unchanged).
#define QCOMP(qblk_, q0w_, qfv, accOv, accSv)                                   \
  do {                                                                          \
    f32x4 st[2][4];                                                             \
    for (int qh = 0; qh < 2; qh++)                                              \
      for (int mt = 0; mt < 4; mt++) st[qh][mt] = zero;                         \
    __builtin_amdgcn_s_setprio(1);                                              \
    _Pragma("unroll")                                                           \
    for (int ks = 0; ks < 2; ks++)                                              \
      _Pragma("unroll")                                                         \
      for (int mt = 0; mt < 4; mt++) {                                          \
        bf16x8 kf = *(const bf16x8*)&Ks2[cur][mt * 16 + lcol]                   \
                                        [((ks * 4 + lrow) ^ rsw) * 8];          \
        st[0][mt] = __builtin_amdgcn_mfma_f32_16x16x32_bf16(kf, qfv[0][ks],     \
                                                            st[0][mt], 0, 0, 0);\
        st[1][mt] = __builtin_amdgcn_mfma_f32_16x16x32_bf16(kf, qfv[1][ks],     \
                                                            st[1][mt], 0, 0, 0);\
      }                                                                         \
    __builtin_amdgcn_s_setprio(0);                                              \
    if (j >= 2 * (qblk_)) {                                                     \
      _Pragma("unroll")                                                         \
      for (int qh = 0; qh < 2; qh++) {                                          \
        int q_g = (q0w_) + qh * 16 + lcol;                                      \
        _Pragma("unroll")                                                       \
        for (int mt = 0; mt < 4; mt++)                                          \
          for (int r = 0; r < 4; r++) {                                         \
            int kv_g = j * 64 + mt * 16 + lrow * 4 + r;                         \
            if (kv_g > q_g) st[qh][mt][r] = -1e30f;                             \
          }                                                                     \
      }                                                                         \
    }                                                                           \
    _Pragma("unroll")                                                           \
    for (int qh = 0; qh < 2; qh++)                                              \
      for (int mt = 0; mt < 4; mt++)                                            \
        for (int r = 0; r < 4; r++)                                             \
          st[qh][mt][r] = __builtin_amdgcn_exp2f(st[qh][mt][r]);                \
    _Pragma("unroll")                                                           \
    for (int qh = 0; qh < 2; qh++)                                              \
      for (int mt = 0; mt < 4; mt++) {                                          \
        uint2 pk;                                                               \
        pk.x = pkbf(st[qh][mt][0], st[qh][mt][1]);                              \
        pk.y = pkbf(st[qh][mt][2], st[qh][mt][3]);                              \
        int sl = ((2 * mt + (lrow >> 1)) ^ rsw) * 8 + (lrow & 1) * 4;           \
        *(uint2*)&Ps[wave][qh * 16 + lcol][sl] = pk;                            \
      }                                                                         \
    __builtin_amdgcn_s_setprio(1);                                              \
    _Pragma("unroll")                                                           \
    for (int ks = 0; ks < 2; ks++) {                                            \
      int ch = ((ks * 4 + lrow) ^ rsw) * 8;                                     \
      bf16x8 pf0 = *(const bf16x8*)&Ps[wave][lcol][ch];                         \
      bf16x8 pf1 = *(const bf16x8*)&Ps[wave][16 + lcol][ch];                    \
      accSv[0] = __builtin_amdgcn_mfma_f32_16x16x32_bf16(af1, pf0, accSv[0],    \
                                                         0, 0, 0);              \
      accSv[1] = __builtin_amdgcn_mfma_f32_16x16x32_bf16(af1, pf1, accSv[1],    \
                                                         0, 0, 0);              \
      _Pragma("unroll")                                                         \
      for (int mt = 0; mt < 4; mt++) {                                          \
        bf16x8 vf = *(const bf16x8*)&Vs2[cur][mt * 16 + lcol][ch];              \
        accOv[0][mt] = __builtin_amdgcn_mfma_f32_16x16x32_bf16(vf, pf0,         \
                                                    accOv[0][mt], 0, 0, 0);     \
        accOv[1][mt] = __builtin_amdgcn_mfma_f32_16x16x32_bf16(vf, pf1,         \
                                                    accOv[1][mt], 0, 0, 0);     \
      }                                                                         \
    }                                                                           \
    __builtin_amdgcn_s_setprio(0);                                              \
  } while (0)

__global__ __launch_bounds__(256) void flash_kernel(
    const ushort* __restrict__ qb, const ushort* __restrict__ kb,
    const ushort* __restrict__ vtb, ushort* __restrict__ ob) {
  __shared__ ushort Ks2[2][64][64];  // 16 KB  [buf][kv][hd] (swizzled chunks)
  __shared__ ushort Vs2[2][64][64];  // 16 KB  [buf][hd][kv] (swizzled chunks)
  __shared__ ushort Ps[4][32][64];   // 16 KB  per-wave P^T strip (swizzled)
  int tid = threadIdx.x;
  int wave = tid >> 6, lane = tid & 63, lrow = lane >> 4, lcol = lane & 15;

  int bid = blockIdx.x + (blockIdx.y << 3);  // grid (8,64) -> 0..511
  int xcd = bid & 7;                         // HW round-robin XCD id
  int slot = bid >> 3;                       // 0..63 per XCD
  int phase = slot >> 5;                     // slot s and s+32 -> same CU
  int j5 = slot & 31;
  int pm = j5 & 7;
  int bh = xcd * 8 + (j5 >> 3) + phase * 4;  // 8 bh per XCD -> K/V L2-resident
  int p = phase ? 7 - pm : pm;               // CU pair carries (p, 7-p): 50 units
  int qbA = 15 - p, qbB = p;
  int b = bh >> 4, h = bh & 15;
  const ushort* qp = qb + (size_t)bh * T_ * HD_;
  const ushort* kh = kb + (size_t)bh * T_ * HD_;
  const ushort* vh = vtb + (size_t)bh * HD_ * T_;

  int njA = 2 * qbA + 2, njB = 2 * qbB + 2;  // B's tiles are a prefix of A's

  int r0 = tid >> 3, dc = tid & 7;          // staging: row, 16B chunk
  int wsl = (dc ^ (r0 & 7)) * 8;            // swizzled slot (ushort offset)
  int rsw = lcol & 7;                       // read-side swizzle key

  uint4 kr0, kr1, vr0, vr1;                 // prefetch regs (one KV tile)
  auto gload = [&](int jt) {
    kr0 = *(const uint4*)&kh[(size_t)(jt * 64 + r0) * HD_ + dc * 8];
    kr1 = *(const uint4*)&kh[(size_t)(jt * 64 + r0 + 32) * HD_ + dc * 8];
    vr0 = *(const uint4*)&vh[(size_t)r0 * T_ + jt * 64 + dc * 8];
    vr1 = *(const uint4*)&vh[(size_t)(r0 + 32) * T_ + jt * 64 + dc * 8];
  };
  auto swrite = [&](int buf) {
    *(uint4*)&Ks2[buf][r0][wsl] = kr0;
    *(uint4*)&Ks2[buf][r0 + 32][wsl] = kr1;   // (r0+32)&7 == r0&7
    *(uint4*)&Vs2[buf][r0][wsl] = vr0;
    *(uint4*)&Vs2[buf][r0 + 32][wsl] = vr1;
  };

  // constant ones-row A-fragment: A[m=0][*]=1, A[m>0][*]=0 (m = lcol)
  bf16x8 af1;
  {
    __bf16 ov = (__bf16)((lcol == 0) ? 1.0f : 0.0f);
    for (int i2 = 0; i2 < 8; i2++) af1[i2] = ov;
  }

  f32x4 zero = {0.f, 0.f, 0.f, 0.f};

  // prologue: tile 0 -> buf0; prefetch tile 1
  gload(0);
  swrite(0);
  gload(1);
  __syncthreads();

  int q0wA = qbA * 128 + wave * 32, q0wB = qbB * 128 + wave * 32;
  bf16x8 qfA[2][2], qfB[2][2];
#pragma unroll
  for (int qh = 0; qh < 2; qh++)
#pragma unroll
    for (int ks = 0; ks < 2; ks++) {
      qfA[qh][ks] = *(const bf16x8*)&qp[(size_t)(q0wA + qh * 16 + lcol) * HD_ +
                                        ks * 32 + lrow * 8];
      qfB[qh][ks] = *(const bf16x8*)&qp[(size_t)(q0wB + qh * 16 + lcol) * HD_ +
                                        ks * 32 + lrow * 8];
    }

  f32x4 accOA[2][4], accOB[2][4];
  f32x4 accSA[2], accSB[2];
#pragma unroll
  for (int qh = 0; qh < 2; qh++) {
    accSA[qh] = zero; accSB[qh] = zero;
    for (int mt = 0; mt < 4; mt++) { accOA[qh][mt] = zero; accOB[qh][mt] = zero; }
  }

  for (int j = 0; j < njA; j++) {
    int cur = j & 1;
    if (j * 64 <= q0wA + 31) QCOMP(qbA, q0wA, qfA, accOA, accSA);
    if (j * 64 <= q0wB + 31) QCOMP(qbB, q0wB, qfB, accOB, accSB);
    // stage next tile (regs hold tile j+1) into the other buffer; its old
    // readers finished before the PREVIOUS barrier.
    if (j + 1 < njA) swrite(cur ^ 1);
    if (j + 2 < njA) gload(j + 2);
    __syncthreads();  // publish writes for next iteration
  }
  (void)njB;

  // epilogue per q-block / q-half
#pragma unroll
  for (int qh = 0; qh < 2; qh++) {
    float lsum = __shfl(accSA[qh][0], lcol);
    float linv = 1.f / lsum;
    int t = q0wA + qh * 16 + lcol;
    size_t base2 = ((size_t)b * T_ + t) * D_ + h * HD_;
#pragma unroll
    for (int mt = 0; mt < 4; mt++) {
      uint2 pk;
      pk.x = pkbf(accOA[qh][mt][0] * linv, accOA[qh][mt][1] * linv);
      pk.y = pkbf(accOA[qh][mt][2] * linv, accOA[qh][mt][3] * linv);
      *(uint2*)&ob[base2 + mt * 16 + lrow * 4] = pk;
    }
  }
#pragma unroll
  for (int qh = 0; qh < 2; qh++) {
    float lsum = __shfl(accSB[qh][0], lcol);
    float linv = 1.f / lsum;
    int t = q0wB + qh * 16 + lcol;
    size_t base2 = ((size_t)b * T_ + t) * D_ + h * HD_;
#pragma unroll
    for (int mt = 0; mt < 4; mt++) {
      uint2 pk;
      pk.x = pkbf(accOB[qh][mt][0] * linv, accOB[qh][mt][1] * linv);
      pk.y = pkbf(accOB[qh][mt][2] * linv, accOB[qh][mt][3] * linv);
      *(uint2*)&ob[base2 + mt * 16 + lrow * 4] = pk;
    }
  }
}

extern "C" void kernel_launch(void* const* d_in, const int* in_sizes, int n_in,
                              void* d_out, int out_size, void* d_ws, size_t ws_size,
                              hipStream_t stream) {
  (void)in_sizes; (void)n_in; (void)out_size; (void)ws_size;
  const float* x  = (const float*)d_in[0];
  const float* wq = (const float*)d_in[1];
  const float* bq = (const float*)d_in[2];
  const float* wk = (const float*)d_in[3];
  const float* bk = (const float*)d_in[4];
  const float* wv = (const float*)d_in[5];
  const float* bv = (const float*)d_in[6];
  const float* wo = (const float*)d_in[7];
  const float* bo = (const float*)d_in[8];
  float* out = (float*)d_out;

  char* ws = (char*)d_ws;
  ushort* xb     = (ushort*)(ws);              // 16 MB  x as bf16 (M x K)
  ushort* wt_qkv = (ushort*)(ws + 16777216);   // 6 MB   [wq|wk|wv]^T (3072 x 1024)
  ushort* wt_o   = (ushort*)(ws + 23068672);   // 2 MB   wo^T
  ushort* qb     = (ushort*)(ws + 25165824);   // 16 MB  Q (B,H,T,HD), pre-scaled
  ushort* kb     = (ushort*)(ws + 41943040);   // 16 MB  K (B,H,T,HD)
  ushort* vtb    = (ushort*)(ws + 58720256);   // 16 MB  V (B,H,HD,T)
  ushort* ob     = (ushort*)(ws + 75497472);   // 16 MB  attn out (B,T,D)

  // allow 144KB dynamic LDS for the pipelined mode-0 GEMM (host attr, idempotent)
  hipFuncSetAttribute((const void*)gemm_pipe_kernel,
                      hipFuncAttributeMaxDynamicSharedMemorySize, 147456);

  cast_x_kernel<<<8192, 256, 0, stream>>>(x, xb);
  transpose_w_kernel<<<dim3(32, 32, 4), 256, 0, stream>>>(wq, wk, wv, wo, wt_qkv, wt_o);
  gemm_pipe_kernel<<<dim3(24, 32), 512, 147456, stream>>>(xb, wt_qkv, bq, bk, bv,
                                                          qb, kb, vtb);
  flash_kernel<<<dim3(8, 64), 256, 0, stream>>>(qb, kb, vtb, ob);
  gemm_o_kernel<<<dim3(8, 64), 256, 0, stream>>>(ob, wt_o, bo, out);
}

// Round 8
// 232.729 us; speedup vs baseline: 1.1035x; 1.0214x over previous
//
#include <hip/hip_runtime.h>

typedef __bf16 bf16x8 __attribute__((ext_vector_type(8)));
typedef float f32x4 __attribute__((ext_vector_type(4)));

#define B_ 4
#define T_ 2048
#define D_ 1024
#define H_ 16
#define HD_ 64
#define M_ 8192
// 1/sqrt(64) * log2(e), folded into Q so softmax uses exp2
#define QSCALE 0.1803368801111204f

__device__ __forceinline__ ushort f2b(float f) {
  union { float f; unsigned u; } v; v.f = f;
  unsigned u = v.u;
  return (ushort)((u + 0x7FFFu + ((u >> 16) & 1u)) >> 16);
}

// pack two floats to bf16 pair (round-half-up: +0x8000 then take hi16)
__device__ __forceinline__ unsigned pkbf(float a, float b) {
  union { float f; unsigned u; } va, vb; va.f = a; vb.f = b;
  return __builtin_amdgcn_perm(vb.u + 0x8000u, va.u + 0x8000u, 0x07060302u);
}

// async global->LDS, 16B per lane. LDS dest must be wave-uniform base + lane*16.
__device__ __forceinline__ void gll16(const void* g, void* l) {
  __builtin_amdgcn_global_load_lds(
      (const __attribute__((address_space(1))) unsigned*)g,
      (__attribute__((address_space(3))) unsigned*)l, 16, 0, 0);
}

// Merged prep: blocks [0,8192) cast x f32->bf16; blocks [8192,12288) do the
// 32x32 tiled weight transpose+cast. One launch instead of two (saves a
// serialized dispatch gap ~10us; both are pure producers for gemm_pipe).
__global__ __launch_bounds__(256) void prep_kernel(
    const float* __restrict__ x,
    const float* __restrict__ wq, const float* __restrict__ wk,
    const float* __restrict__ wv, const float* __restrict__ wo,
    ushort* __restrict__ xb, ushort* __restrict__ wt_qkv,
    ushort* __restrict__ wt_o) {
  __shared__ float tile[32][33];
  int bid = blockIdx.x;
  if (bid < 8192) {  // cast x
    int idx = bid * 256 + threadIdx.x;
    float4 v = ((const float4*)x)[idx];
    ushort4 o;
    o.x = f2b(v.x); o.y = f2b(v.y); o.z = f2b(v.z); o.w = f2b(v.w);
    ((ushort4*)xb)[idx] = o;
  } else {           // transpose weights: dst[n][k] = src[k][n]
    int i2 = bid - 8192;
    int z = i2 >> 10;
    int rem = i2 & 1023;
    const float* src = (z == 0) ? wq : (z == 1) ? wk : (z == 2) ? wv : wo;
    ushort* dst = (z < 3) ? (wt_qkv + (size_t)z * D_ * D_) : wt_o;
    int n0 = (rem & 31) * 32, k0 = (rem >> 5) * 32;
    int tx = threadIdx.x & 31, ty = threadIdx.x >> 5;
    for (int i = 0; i < 4; i++) {
      int r = ty + i * 8;
      tile[r][tx] = src[(size_t)(k0 + r) * D_ + n0 + tx];
    }
    __syncthreads();
    for (int i = 0; i < 4; i++) {
      int r = ty + i * 8;
      dst[(size_t)(n0 + r) * D_ + k0 + tx] = f2b(tile[tx][r]);
    }
  }
}

// MODE-0 GEMM (QKV projections). Round-8 restructure of the r6 pipeline:
// ONE phase per K-tile: {16 ds_read_b128 (both K=32 slices); stage-issue tile
// t+2; 32 MFMA; vmcnt(6); s_barrier}. One barrier per K-tile (was 4) and no
// sched_barrier pins: both phases of a K-tile read the SAME staged buffer, so
// the mid-phase barrier protected nothing, and the pins blocked the
// compiler's fine-grained lgkmcnt interleave of reads with MFMAs (m141
// lesson). Hazards: reads of tile t are covered by end-of-(t-1) vmcnt(6) +
// barrier (all waves); stage of t+2 overwrites buf (t-1)%3 whose readers all
// passed that same barrier. Barriers are asm with "memory" clobber so LDS
// reads cannot be compiler-hoisted across (raw s_barrier has no fence).
// Accumulation sequence per acc element identical -> bit-exact.
__global__ __launch_bounds__(512) void gemm_pipe_kernel(
    const ushort* __restrict__ A, const ushort* __restrict__ Bt,
    const float* __restrict__ bias_q, const float* __restrict__ bias_k,
    const float* __restrict__ bias_v,
    ushort* __restrict__ qb, ushort* __restrict__ kb, ushort* __restrict__ vtb) {
  extern __shared__ char lds_raw[];
  ushort (*As)[256][64] = (ushort (*)[256][64])lds_raw;            // 3x32KB
  ushort (*Bs)[128][64] = (ushort (*)[128][64])(lds_raw + 98304);  // 3x16KB
  int tid = threadIdx.x;
  int wave = tid >> 6, lane = tid & 63, lrow = lane >> 4, lcol = lane & 15;
  int wr = wave >> 1, wc = wave & 1;  // 4M x 2N wave grid

  // XCD-chunked remap; nwg = 768, %8==0.
  int gx = gridDim.x;
  int nwg = gx * gridDim.y;
  int orig = blockIdx.x + gx * blockIdx.y;
  int work = (orig & 7) * (nwg >> 3) + (orig >> 3);
  int m0 = (work / gx) * 256, n0 = (work % gx) * 128;

  // staging geometry: 512 threads; A-unit = 128 rows x 64 cols (16KB) ->
  // 2 gll16/thread; per K-tile: A-unit0, A-unit1, B (3 units, 6 loads).
  int r_s = tid >> 3, c_s = tid & 7;
  int scv = c_s ^ (r_s & 7);  // pre-swizzled source chunk ((r+64k)&7 == r&7)
  const ushort* aB = A + (size_t)(m0 + r_s) * D_ + scv * 8;
  const ushort* bB = Bt + (size_t)(n0 + r_s) * D_ + scv * 8;

  auto stageA = [&](int buf, int t, int u) {
    const ushort* s = aB + (size_t)u * 128 * D_ + t * 64;
    char* d = (char*)&As[buf][0][0] + u * 16384 + tid * 16;
    gll16(s, d);
    gll16(s + (size_t)64 * D_, d + 8192);
  };
  auto stageB = [&](int buf, int t) {
    const ushort* s = bB + t * 64;
    char* d = (char*)&Bs[buf][0][0] + tid * 16;
    gll16(s, d);
    gll16(s + (size_t)64 * D_, d + 8192);
  };

  f32x4 zero = {0.f, 0.f, 0.f, 0.f};
  f32x4 acc[4][4];
  for (int i = 0; i < 4; i++)
    for (int j = 0; j < 4; j++) acc[i][j] = zero;

  int swz = lcol & 7;

  // prologue: stage tiles 0 and 1 (FIFO order matters for vmcnt accounting)
  stageA(0, 0, 0); stageA(0, 0, 1); stageB(0, 0);
  stageA(1, 1, 0); stageA(1, 1, 1); stageB(1, 1);
  asm volatile("s_waitcnt vmcnt(6)" ::: "memory");  // tile 0 landed (own)
  asm volatile("s_barrier" ::: "memory");           // -> all waves' tile 0 in

#pragma unroll
  for (int t = 0; t < 16; ++t) {
    int buf = t % 3;          // compile-time after unroll
    int nb = (t + 2) % 3;
    // read ALL frags of this K-tile (both K=32 slices); compiler interleaves
    // the dependent MFMAs with counted lgkmcnt as reads complete.
    bf16x8 af[2][4], bf[2][4];
#pragma unroll
    for (int ks = 0; ks < 2; ++ks) {
      int ch = ((ks * 4 + lrow) ^ swz) * 8;
#pragma unroll
      for (int mt = 0; mt < 4; mt++)
        af[ks][mt] = *(const bf16x8*)&As[buf][wr * 64 + mt * 16 + lcol][ch];
#pragma unroll
      for (int nt = 0; nt < 4; nt++)
        bf[ks][nt] = *(const bf16x8*)&Bs[buf][wc * 64 + nt * 16 + lcol][ch];
    }
    if (t + 2 < 16) {  // async stage of tile t+2 (its buffer's readers all
      stageA(nb, t + 2, 0); stageA(nb, t + 2, 1); stageB(nb, t + 2);
    }                  // passed the end-of-(t-1) barrier)
    __builtin_amdgcn_s_setprio(1);
#pragma unroll
    for (int ks = 0; ks < 2; ++ks)
#pragma unroll
      for (int mt = 0; mt < 4; mt++)
#pragma unroll
        for (int nt = 0; nt < 4; nt++)
          acc[mt][nt] = __builtin_amdgcn_mfma_f32_16x16x32_bf16(
              af[ks][mt], bf[ks][nt], acc[mt][nt], 0, 0, 0);
    __builtin_amdgcn_s_setprio(0);
    // tile-boundary checkpoint: own loads for tile t+1 complete (t+2 stays
    // in flight -> never drain to 0 in steady state), then barrier so ALL
    // waves' t+1 staging is visible before anyone reads it.
    if (t <= 13) {
      asm volatile("s_waitcnt vmcnt(6)" ::: "memory");
      asm volatile("s_barrier" ::: "memory");
    } else if (t == 14) {
      asm volatile("s_waitcnt vmcnt(0)" ::: "memory");
      asm volatile("s_barrier" ::: "memory");
    }
  }

  {
    int proj = n0 >> 10;  // uniform per block (128 | 1024)
    const float* bias = (proj == 0) ? bias_q : (proj == 1) ? bias_k : bias_v;
    for (int mt = 0; mt < 4; mt++) {
      int gm0 = m0 + wr * 64 + mt * 16 + lrow * 4;  // 4 consecutive t, same b
      int b = gm0 >> 11, tp = gm0 & 2047;
      for (int nt = 0; nt < 4; nt++) {
        int gn = n0 + wc * 64 + nt * 16 + lcol;
        int inner = gn & 1023;
        int h = inner >> 6, hd = inner & 63;
        float bv = bias[inner];
        if (proj == 0) {
          size_t base = ((size_t)(b * H_ + h) * T_ + tp) * HD_ + hd;
          for (int r = 0; r < 4; r++)
            qb[base + (size_t)r * HD_] = f2b((acc[mt][nt][r] + bv) * QSCALE);
        } else if (proj == 1) {
          size_t base = ((size_t)(b * H_ + h) * T_ + tp) * HD_ + hd;
          for (int r = 0; r < 4; r++)
            kb[base + (size_t)r * HD_] = f2b(acc[mt][nt][r] + bv);
        } else {  // V stored transposed: (B,H,HD,T); 4 t's pack into ushort4
          ushort4 pk;
          pk.x = f2b(acc[mt][nt][0] + bv);
          pk.y = f2b(acc[mt][nt][1] + bv);
          pk.z = f2b(acc[mt][nt][2] + bv);
          pk.w = f2b(acc[mt][nt][3] + bv);
          *(ushort4*)&vtb[((size_t)(b * H_ + h) * HD_ + hd) * T_ + tp] = pk;
        }
      }
    }
  }
}

// MODE-1 GEMM (output projection): round-4/5 static 128x128 m97 structure,
// 256 threads, 64KB LDS -> 2 blocks/CU co-residency (measured ~24us).
__global__ __launch_bounds__(256) void gemm_o_kernel(
    const ushort* __restrict__ A, const ushort* __restrict__ Bt,
    const float* __restrict__ bias, float* __restrict__ outf) {
  __shared__ ushort As[2][128][64];  // 32 KB
  __shared__ ushort Bs[2][128][64];  // 32 KB
  int tid = threadIdx.x;
  int wave = tid >> 6, lane = tid & 63, lrow = lane >> 4, lcol = lane & 15;

  int gx = gridDim.x;
  int nwg = gx * gridDim.y;
  int orig = blockIdx.x + gx * blockIdx.y;
  int work = (orig & 7) * (nwg >> 3) + (orig >> 3);
  int m0 = (work / gx) * 128, n0 = (work % gx) * 128;
  int wm = (wave & 1) * 64, wn = (wave >> 1) * 64;

  int rb = tid >> 3;            // 0..31
  int dc = tid & 7;             // dest 16B chunk
  int scv = dc ^ (rb & 7);      // swizzled source chunk
  const ushort* aBase = A + (size_t)(m0 + rb) * D_ + scv * 8;
  const ushort* bBase = Bt + (size_t)(n0 + rb) * D_ + scv * 8;

  f32x4 zero = {0.f, 0.f, 0.f, 0.f};
  f32x4 acc[4][4];
  for (int i = 0; i < 4; i++)
    for (int j = 0; j < 4; j++) acc[i][j] = zero;

  int swz = lcol & 7;

  auto stage = [&](int buf, int k) {
#pragma unroll
    for (int g = 0; g < 4; g++) {
      gll16(aBase + (size_t)(32 * g) * D_ + k, &As[buf][0][0] + tid * 8 + g * 2048);
      gll16(bBase + (size_t)(32 * g) * D_ + k, &Bs[buf][0][0] + tid * 8 + g * 2048);
    }
  };

  stage(0, 0);  // prologue

  for (int k0 = 0; k0 < D_; k0 += 64) {
    int cur = (k0 >> 6) & 1, nxt = cur ^ 1;
    __syncthreads();  // drains vmcnt -> buf[cur] ready; prior reads of nxt done
    if (k0 + 64 < D_) stage(nxt, k0 + 64);  // async, in flight across compute

    for (int ks = 0; ks < 2; ks++) {
      bf16x8 af[4], bf[4];
      int ch = ((ks * 4 + lrow) ^ swz) * 8;
      for (int mt = 0; mt < 4; mt++)
        af[mt] = *(const bf16x8*)&As[cur][wm + mt * 16 + lcol][ch];
      for (int nt = 0; nt < 4; nt++)
        bf[nt] = *(const bf16x8*)&Bs[cur][wn + nt * 16 + lcol][ch];
      for (int mt = 0; mt < 4; mt++)
        for (int nt = 0; nt < 4; nt++)
          acc[mt][nt] = __builtin_amdgcn_mfma_f32_16x16x32_bf16(
              af[mt], bf[nt], acc[mt][nt], 0, 0, 0);
    }
  }

  for (int mt = 0; mt < 4; mt++) {
    int gm0 = m0 + wm + mt * 16 + lrow * 4;
    for (int nt = 0; nt < 4; nt++) {
      int gn = n0 + wn + nt * 16 + lcol;
      float bv = bias[gn];
      for (int r = 0; r < 4; r++)
        outf[(size_t)(gm0 + r) * D_ + gn] = acc[mt][nt][r] + bv;
    }
  }
}

// Causal flash attention, fixed-base softmax (log2-unit scores, exp2, no max
// subtraction — validated). Round-5 structure: MERGED pair loop (unchanged).
#define QCOMP(qblk_, q0w_, qfv, accOv, accSv)                                   \
  do {                                                                          \
    f32x4 st[2][4];                                                             \
    for (int qh = 0; qh < 2; qh++)                                              \
      for (int mt = 0; mt < 4; mt++) st[qh][mt] = zero;                         \
    __builtin_amdgcn_s_setprio(1);                                              \
    _Pragma("unroll")                                                           \
    for (int ks = 0; ks < 2; ks++)                                              \
      _Pragma("unroll")                                                         \
      for (int mt = 0; mt < 4; mt++) {                                          \
        bf16x8 kf = *(const bf16x8*)&Ks2[cur][mt * 16 + lcol]                   \
                                        [((ks * 4 + lrow) ^ rsw) * 8];          \
        st[0][mt] = __builtin_amdgcn_mfma_f32_16x16x32_bf16(kf, qfv[0][ks],     \
                                                            st[0][mt], 0, 0, 0);\
        st[1][mt] = __builtin_amdgcn_mfma_f32_16x16x32_bf16(kf, qfv[1][ks],     \
                                                            st[1][mt], 0, 0, 0);\
      }                                                                         \
    __builtin_amdgcn_s_setprio(0);                                              \
    if (j >= 2 * (qblk_)) {                                                     \
      _Pragma("unroll")                                                         \
      for (int qh = 0; qh < 2; qh++) {                                          \
        int q_g = (q0w_) + qh * 16 + lcol;                                      \
        _Pragma("unroll")                                                       \
        for (int mt = 0; mt < 4; mt++)                                          \
          for (int r = 0; r < 4; r++) {                                         \
            int kv_g = j * 64 + mt * 16 + lrow * 4 + r;                         \
            if (kv_g > q_g) st[qh][mt][r] = -1e30f;                             \
          }                                                                     \
      }                                                                         \
    }                                                                           \
    _Pragma("unroll")                                                           \
    for (int qh = 0; qh < 2; qh++)                                              \
      for (int mt = 0; mt < 4; mt++)                                            \
        for (int r = 0; r < 4; r++)                                             \
          st[qh][mt][r] = __builtin_amdgcn_exp2f(st[qh][mt][r]);                \
    _Pragma("unroll")                                                           \
    for (int qh = 0; qh < 2; qh++)                                              \
      for (int mt = 0; mt < 4; mt++) {                                          \
        uint2 pk;                                                               \
        pk.x = pkbf(st[qh][mt][0], st[qh][mt][1]);                              \
        pk.y = pkbf(st[qh][mt][2], st[qh][mt][3]);                              \
        int sl = ((2 * mt + (lrow >> 1)) ^ rsw) * 8 + (lrow & 1) * 4;           \
        *(uint2*)&Ps[wave][qh * 16 + lcol][sl] = pk;                            \
      }                                                                         \
    __builtin_amdgcn_s_setprio(1);                                              \
    _Pragma("unroll")                                                           \
    for (int ks = 0; ks < 2; ks++) {                                            \
      int ch = ((ks * 4 + lrow) ^ rsw) * 8;                                     \
      bf16x8 pf0 = *(const bf16x8*)&Ps[wave][lcol][ch];                         \
      bf16x8 pf1 = *(const bf16x8*)&Ps[wave][16 + lcol][ch];                    \
      accSv[0] = __builtin_amdgcn_mfma_f32_16x16x32_bf16(af1, pf0, accSv[0],    \
                                                         0, 0, 0);              \
      accSv[1] = __builtin_amdgcn_mfma_f32_16x16x32_bf16(af1, pf1, accSv[1],    \
                                                         0, 0, 0);              \
      _Pragma("unroll")                                                         \
      for (int mt = 0; mt < 4; mt++) {                                          \
        bf16x8 vf = *(const bf16x8*)&Vs2[cur][mt * 16 + lcol][ch];              \
        accOv[0][mt] = __builtin_amdgcn_mfma_f32_16x16x32_bf16(vf, pf0,         \
                                                    accOv[0][mt], 0, 0, 0);     \
        accOv[1][mt] = __builtin_amdgcn_mfma_f32_16x16x32_bf16(vf, pf1,         \
                                                    accOv[1][mt], 0, 0, 0);     \
      }                                                                         \
    }                                                                           \
    __builtin_amdgcn_s_setprio(0);                                              \
  } while (0)

__global__ __launch_bounds__(256) void flash_kernel(
    const ushort* __restrict__ qb, const ushort* __restrict__ kb,
    const ushort* __restrict__ vtb, ushort* __restrict__ ob) {
  __shared__ ushort Ks2[2][64][64];  // 16 KB  [buf][kv][hd] (swizzled chunks)
  __shared__ ushort Vs2[2][64][64];  // 16 KB  [buf][hd][kv] (swizzled chunks)
  __shared__ ushort Ps[4][32][64];   // 16 KB  per-wave P^T strip (swizzled)
  int tid = threadIdx.x;
  int wave = tid >> 6, lane = tid & 63, lrow = lane >> 4, lcol = lane & 15;

  int bid = blockIdx.x + (blockIdx.y << 3);  // grid (8,64) -> 0..511
  int xcd = bid & 7;                         // HW round-robin XCD id
  int slot = bid >> 3;                       // 0..63 per XCD
  int phase = slot >> 5;                     // slot s and s+32 -> same CU
  int j5 = slot & 31;
  int pm = j5 & 7;
  int bh = xcd * 8 + (j5 >> 3) + phase * 4;  // 8 bh per XCD -> K/V L2-resident
  int p = phase ? 7 - pm : pm;               // CU pair carries (p, 7-p): 50 units
  int qbA = 15 - p, qbB = p;
  int b = bh >> 4, h = bh & 15;
  const ushort* qp = qb + (size_t)bh * T_ * HD_;
  const ushort* kh = kb + (size_t)bh * T_ * HD_;
  const ushort* vh = vtb + (size_t)bh * HD_ * T_;

  int njA = 2 * qbA + 2, njB = 2 * qbB + 2;  // B's tiles are a prefix of A's

  int r0 = tid >> 3, dc = tid & 7;          // staging: row, 16B chunk
  int wsl = (dc ^ (r0 & 7)) * 8;            // swizzled slot (ushort offset)
  int rsw = lcol & 7;                       // read-side swizzle key

  uint4 kr0, kr1, vr0, vr1;                 // prefetch regs (one KV tile)
  auto gload = [&](int jt) {
    kr0 = *(const uint4*)&kh[(size_t)(jt * 64 + r0) * HD_ + dc * 8];
    kr1 = *(const uint4*)&kh[(size_t)(jt * 64 + r0 + 32) * HD_ + dc * 8];
    vr0 = *(const uint4*)&vh[(size_t)r0 * T_ + jt * 64 + dc * 8];
    vr1 = *(const uint4*)&vh[(size_t)(r0 + 32) * T_ + jt * 64 + dc * 8];
  };
  auto swrite = [&](int buf) {
    *(uint4*)&Ks2[buf][r0][wsl] = kr0;
    *(uint4*)&Ks2[buf][r0 + 32][wsl] = kr1;   // (r0+32)&7 == r0&7
    *(uint4*)&Vs2[buf][r0][wsl] = vr0;
    *(uint4*)&Vs2[buf][r0 + 32][wsl] = vr1;
  };

  // constant ones-row A-fragment: A[m=0][*]=1, A[m>0][*]=0 (m = lcol)
  bf16x8 af1;
  {
    __bf16 ov = (__bf16)((lcol == 0) ? 1.0f : 0.0f);
    for (int i2 = 0; i2 < 8; i2++) af1[i2] = ov;
  }

  f32x4 zero = {0.f, 0.f, 0.f, 0.f};

  // prologue: tile 0 -> buf0; prefetch tile 1
  gload(0);
  swrite(0);
  gload(1);
  __syncthreads();

  int q0wA = qbA * 128 + wave * 32, q0wB = qbB * 128 + wave * 32;
  bf16x8 qfA[2][2], qfB[2][2];
#pragma unroll
  for (int qh = 0; qh < 2; qh++)
#pragma unroll
    for (int ks = 0; ks < 2; ks++) {
      qfA[qh][ks] = *(const bf16x8*)&qp[(size_t)(q0wA + qh * 16 + lcol) * HD_ +
                                        ks * 32 + lrow * 8];
      qfB[qh][ks] = *(const bf16x8*)&qp[(size_t)(q0wB + qh * 16 + lcol) * HD_ +
                                        ks * 32 + lrow * 8];
    }

  f32x4 accOA[2][4], accOB[2][4];
  f32x4 accSA[2], accSB[2];
#pragma unroll
  for (int qh = 0; qh < 2; qh++) {
    accSA[qh] = zero; accSB[qh] = zero;
    for (int mt = 0; mt < 4; mt++) { accOA[qh][mt] = zero; accOB[qh][mt] = zero; }
  }

  for (int j = 0; j < njA; j++) {
    int cur = j & 1;
    if (j * 64 <= q0wA + 31) QCOMP(qbA, q0wA, qfA, accOA, accSA);
    if (j * 64 <= q0wB + 31) QCOMP(qbB, q0wB, qfB, accOB, accSB);
    // stage next tile (regs hold tile j+1) into the other buffer; its old
    // readers finished before the PREVIOUS barrier.
    if (j + 1 < njA) swrite(cur ^ 1);
    if (j + 2 < njA) gload(j + 2);
    __syncthreads();  // publish writes for next iteration
  }
  (void)njB;

  // epilogue per q-block / q-half
#pragma unroll
  for (int qh = 0; qh < 2; qh++) {
    float lsum = __shfl(accSA[qh][0], lcol);
    float linv = 1.f / lsum;
    int t = q0wA + qh * 16 + lcol;
    size_t base2 = ((size_t)b * T_ + t) * D_ + h * HD_;
#pragma unroll
    for (int mt = 0; mt < 4; mt++) {
      uint2 pk;
      pk.x = pkbf(accOA[qh][mt][0] * linv, accOA[qh][mt][1] * linv);
      pk.y = pkbf(accOA[qh][mt][2] * linv, accOA[qh][mt][3] * linv);
      *(uint2*)&ob[base2 + mt * 16 + lrow * 4] = pk;
    }
  }
#pragma unroll
  for (int qh = 0; qh < 2; qh++) {
    float lsum = __shfl(accSB[qh][0], lcol);
    float linv = 1.f / lsum;
    int t = q0wB + qh * 16 + lcol;
    size_t base2 = ((size_t)b * T_ + t) * D_ + h * HD_;
#pragma unroll
    for (int mt = 0; mt < 4; mt++) {
      uint2 pk;
      pk.x = pkbf(accOB[qh][mt][0] * linv, accOB[qh][mt][1] * linv);
      pk.y = pkbf(accOB[qh][mt][2] * linv, accOB[qh][mt][3] * linv);
      *(uint2*)&ob[base2 + mt * 16 + lrow * 4] = pk;
    }
  }
}

extern "C" void kernel_launch(void* const* d_in, const int* in_sizes, int n_in,
                              void* d_out, int out_size, void* d_ws, size_t ws_size,
                              hipStream_t stream) {
  (void)in_sizes; (void)n_in; (void)out_size; (void)ws_size;
  const float* x  = (const float*)d_in[0];
  const float* wq = (const float*)d_in[1];
  const float* bq = (const float*)d_in[2];
  const float* wk = (const float*)d_in[3];
  const float* bk = (const float*)d_in[4];
  const float* wv = (const float*)d_in[5];
  const float* bv = (const float*)d_in[6];
  const float* wo = (const float*)d_in[7];
  const float* bo = (const float*)d_in[8];
  float* out = (float*)d_out;

  char* ws = (char*)d_ws;
  ushort* xb     = (ushort*)(ws);              // 16 MB  x as bf16 (M x K)
  ushort* wt_qkv = (ushort*)(ws + 16777216);   // 6 MB   [wq|wk|wv]^T (3072 x 1024)
  ushort* wt_o   = (ushort*)(ws + 23068672);   // 2 MB   wo^T
  ushort* qb     = (ushort*)(ws + 25165824);   // 16 MB  Q (B,H,T,HD), pre-scaled
  ushort* kb     = (ushort*)(ws + 41943040);   // 16 MB  K (B,H,T,HD)
  ushort* vtb    = (ushort*)(ws + 58720256);   // 16 MB  V (B,H,HD,T)
  ushort* ob     = (ushort*)(ws + 75497472);   // 16 MB  attn out (B,T,D)

  // allow 144KB dynamic LDS for the pipelined mode-0 GEMM (host attr, idempotent)
  hipFuncSetAttribute((const void*)gemm_pipe_kernel,
                      hipFuncAttributeMaxDynamicSharedMemorySize, 147456);

  prep_kernel<<<12288, 256, 0, stream>>>(x, wq, wk, wv, wo, xb, wt_qkv, wt_o);
  gemm_pipe_kernel<<<dim3(24, 32), 512, 147456, stream>>>(xb, wt_qkv, bq, bk, bv,
                                                          qb, kb, vtb);
  flash_kernel<<<dim3(8, 64), 256, 0, stream>>>(qb, kb, vtb, ob);
  gemm_o_kernel<<<dim3(8, 64), 256, 0, stream>>>(ob, wt_o, bo, out);
}